// Round 14
// baseline (257.555 us; speedup 1.0000x reference)
//
#include <hip/hip_runtime.h>
#include <hip/hip_bf16.h>

#define CDIV(a,b) (((a)+(b)-1)/(b))

typedef __attribute__((ext_vector_type(8))) short short8;   // 8 bf16 (4 VGPRs)
typedef __attribute__((ext_vector_type(4))) float f32x4;    // MFMA C/D frag

static __device__ inline short f2bf(float f) {
    union { __hip_bfloat16 h; short s; } u;
    u.h = __float2bfloat16(f);
    return u.s;
}
static __device__ inline ushort f2bfu(float f) { return (ushort)f2bf(f); }
static __device__ inline float bfu_lo(uint v) { return __uint_as_float(v << 16); }
static __device__ inline float bfu_hi(uint v) { return __uint_as_float(v & 0xffff0000u); }

// ---------------- weight prep ----------------

__global__ __launch_bounds__(512) void k_init(const float* __restrict__ W1,
                                              short* __restrict__ W1t,
                                              const float* __restrict__ Wmu,
                                              const float* __restrict__ Wvar,
                                              short* __restrict__ Wcat) {
    int i = blockIdx.x * 512 + threadIdx.x;
    if (i < 128 * 256) {                       // W1t[col][k] = bf16(W1[k][col]), K=256
        int k = i % 256, col = i / 256;
        W1t[i] = f2bf(W1[(size_t)k * 128 + col]);
    } else if (i < 2 * 128 * 256) {            // Wcat[col][k], K=128: col<128 Wmu, else Wvar
        int j = i - 128 * 256;
        int k = j & 127, col = j >> 7;
        float v = (col < 128) ? Wmu[(size_t)k * 128 + col] : Wvar[(size_t)k * 128 + (col - 128)];
        Wcat[j] = f2bf(v);
    }
}

// ---------------- fat kernel: GEMM1 (blocks < nGB) || coarse histogram (blocks >= nGB) ----------------
// GEMM1: xw[n,128] = bf16( x[n,256] @ W1 ), 8 waves x 16 rows = 128 rows/block (782 blocks
// -> ~4 blocks/CU; R13's 256-row tile left the grid at 1.5 blocks/CU, occupancy 36%).
// HIST: bucket = col>>8 (256 cols); per-block LDS histogram -> bhist[bucket*NBH + hb].
// NOTE: scatter (k_bucket) uses the SAME NBH-block / chunkBH decomposition (R11 lesson).

__global__ __launch_bounds__(512) void k_fat(const float* __restrict__ A,
                                             const short* __restrict__ Bt,
                                             ushort* __restrict__ C, int n, int nGB,
                                             const int* __restrict__ coli,
                                             int* __restrict__ bhist,
                                             int E, int chunkBH, int nbk, int NBH) {
    const int K = 256, KH = 128;
    __shared__ short Blds[128 * KH];           // 32 KB (hist path reuses as int*)
    int t = threadIdx.x;

    if (blockIdx.x >= nGB) {                   // ---- histogram path ----
        int* h = (int*)Blds;
        int b = blockIdx.x - nGB;
        for (int i = t; i < nbk; i += 512) h[i] = 0;
        __syncthreads();
        int e0 = b * chunkBH, e1 = min(E, e0 + chunkBH);
        for (int e = e0 + t; e < e1; e += 512)
            atomicAdd(&h[coli[e] >> 8], 1);
        __syncthreads();
        for (int i = t; i < nbk; i += 512)
            bhist[i * NBH + b] = h[i];
        return;
    }

    // ---- GEMM1 path: 128 rows/block, each wave one 16-row frag ----
    int wave = t >> 6, lane = t & 63;
    int lg = lane >> 4, lr = lane & 15;
    long row_base = (long)blockIdx.x * 128 + wave * 16;

    long ra0 = row_base + lr; if (ra0 > n - 1) ra0 = n - 1;   // clamped, stores guarded

    f32x4 acc[8];
    #pragma unroll
    for (int j = 0; j < 8; ++j) acc[j] = (f32x4){0.f, 0.f, 0.f, 0.f};

    const float* pa0 = A + ra0 * K + lg * 8;

    #pragma unroll
    for (int p = 0; p < 2; ++p) {
        if (p) __syncthreads();
        const int CHK = KH / 8;
        for (int c = t; c < 128 * CHK; c += 512) {
            int colw = c / CHK;
            int kb  = (c % CHK) * 16;
            int dst = colw * (KH * 2) + (kb ^ ((colw & 7) << 4));
            *(float4*)((char*)Blds + dst) =
                *(const float4*)((const char*)Bt + (size_t)colw * (K * 2) + p * (KH * 2) + kb);
        }
        __syncthreads();

        for (int k0 = 0; k0 < KH; k0 += 32) {
            int kg = p * KH + k0;
            float4 x0 = *(const float4*)(pa0 + kg);
            float4 x1 = *(const float4*)(pa0 + kg + 4);
            short8 a0;
            a0[0]=f2bf(x0.x); a0[1]=f2bf(x0.y); a0[2]=f2bf(x0.z); a0[3]=f2bf(x0.w);
            a0[4]=f2bf(x1.x); a0[5]=f2bf(x1.y); a0[6]=f2bf(x1.z); a0[7]=f2bf(x1.w);

            int kb = (k0 + lg * 8) * 2;
            #pragma unroll
            for (int cb = 0; cb < 8; ++cb) {
                int colm = cb * 16 + lr;
                short8 bfr = *(short8*)((char*)Blds + colm * (KH * 2) + (kb ^ ((colm & 7) << 4)));
                acc[cb] = __builtin_amdgcn_mfma_f32_16x16x32_bf16(a0, bfr, acc[cb], 0, 0, 0);
            }
        }
    }

    #pragma unroll
    for (int cb = 0; cb < 8; ++cb) {
        int colm = cb * 16 + lr;
        #pragma unroll
        for (int r = 0; r < 4; ++r) {
            long row = row_base + lg * 4 + r;
            if (row < n) C[row * 128 + colm] = f2bfu(acc[cb][r]);
        }
    }
}

// ---------------- scanA over bhist (block-local exclusive + unscanned block totals) ----------------
// Consumers scan the <=128 block totals inline (dropped kscanB launch).

__global__ __launch_bounds__(256) void kscanA(const int* __restrict__ in,
                                              int* __restrict__ out,
                                              int* __restrict__ part, int n) {
    int t = threadIdx.x;
    int base = blockIdx.x * 1024 + t * 4;
    int v0 = (base + 0 < n) ? in[base + 0] : 0;
    int v1 = (base + 1 < n) ? in[base + 1] : 0;
    int v2 = (base + 2 < n) ? in[base + 2] : 0;
    int v3 = (base + 3 < n) ? in[base + 3] : 0;
    int tsum = v0 + v1 + v2 + v3;
    int lane = t & 63, wv = t >> 6;
    int val = tsum;
    #pragma unroll
    for (int d = 1; d < 64; d <<= 1) {
        int u = __shfl_up(val, d, 64);
        if (lane >= d) val += u;
    }
    __shared__ int ws[4];
    if (lane == 63) ws[wv] = val;
    __syncthreads();
    int woff = 0;
    #pragma unroll
    for (int i = 0; i < 4; ++i) if (i < wv) woff += ws[i];
    int excl = woff + val - tsum;
    if (base + 0 < n) out[base + 0] = excl;  excl += v0;
    if (base + 1 < n) out[base + 1] = excl;  excl += v1;
    if (base + 2 < n) out[base + 2] = excl;  excl += v2;
    if (base + 3 < n) out[base + 3] = excl;
    if (t == 255) part[blockIdx.x] = woff + val;   // block total (unscanned)
}

// inline scan of <=128 part totals into pscan[] (exclusive); call from 512-thread blocks
static __device__ inline void scan_parts(const int* __restrict__ part, int nparts,
                                         int* pscan /* LDS[128] */, int* wtot /* LDS[2] */) {
    int t = threadIdx.x;
    int lane = t & 63;
    if (t < 128) {
        int v = (t < nparts) ? part[t] : 0;
        int val = v;
        #pragma unroll
        for (int d = 1; d < 64; d <<= 1) {
            int u = __shfl_up(val, d, 64);
            if (lane >= d) val += u;
        }
        if (lane == 63) wtot[t >> 6] = val;
        pscan[t] = val - v;                    // exclusive within wave
    }
    __syncthreads();
    if (t >= 64 && t < 128) pscan[t] += wtot[0];
    __syncthreads();
}

// S3: scatter edges into bucket-grouped array (LDS cursor per bucket), one 8B store/edge.
// gridDim.x == NBH and chunk == chunkBH (must match histogram decomposition).
__global__ __launch_bounds__(512) void k_bucket(const int* __restrict__ rowi,
                                                const int* __restrict__ coli,
                                                const float* __restrict__ ew,
                                                const int* __restrict__ excl,
                                                const int* __restrict__ part, int nparts,
                                                int2* __restrict__ bxw,
                                                int E, int chunk, int nbk) {
    __shared__ int cur[512];                   // nbk <= 512
    __shared__ int pscan[128], wtot[2];
    int b = blockIdx.x, t = threadIdx.x, nblk = gridDim.x;
    for (int i = t; i < nbk; i += 512) cur[i] = 0;
    scan_parts(part, nparts, pscan, wtot);     // includes syncthreads
    int e0 = b * chunk, e1 = min(E, e0 + chunk);
    for (int e = e0 + t; e < e1; e += 512) {
        int c = coli[e];
        int bk = c >> 8;
        int idx = bk * nblk + b;
        int pos = excl[idx] + pscan[idx >> 10] + atomicAdd(&cur[bk], 1);
        bxw[pos] = make_int2(((c & 255) << 17) | rowi[e], __float_as_int(ew[e]));
    }
}

// S4: per-col count + fixed-point ew sum + LOCAL scan -> row_ptr + dis (one block/bucket, 256 cols)
__global__ __launch_bounds__(512) void k_fine2(const int2* __restrict__ bxw,
                                               const int* __restrict__ excl,
                                               const int* __restrict__ part, int nparts,
                                               int* __restrict__ row_ptr,
                                               float* __restrict__ dis,
                                               int E, int nblk, int n) {
    __shared__ int cnt[256], ews[256];
    __shared__ int ws2[4];
    __shared__ int pscan[128], wtot[2];
    int bk = blockIdx.x, t = threadIdx.x;
    if (t < 256) { cnt[t] = 0; ews[t] = 0; }
    scan_parts(part, nparts, pscan, wtot);
    int i0 = bk * nblk;
    int s0 = excl[i0] + pscan[i0 >> 10];
    int s1 = E;
    if (bk + 1 < gridDim.x) {
        int i1 = (bk + 1) * nblk;
        s1 = excl[i1] + pscan[i1 >> 10];
    }
    for (int p = s0 + t; p < s1; p += 512) {
        int2 u = bxw[p];
        int cl = u.x >> 17;
        atomicAdd(&cnt[cl], 1);
        int q = (int)(__int_as_float(u.y) * 16777216.0f + 0.5f);
        atomicAdd(&ews[cl], q);
    }
    __syncthreads();
    // local exclusive scan over cnt[256] (threads 0..255 = waves 0..3)
    int v = 0, val = 0;
    int lane = t & 63, wv = t >> 6;
    if (t < 256) {
        v = cnt[t];
        val = v;
        #pragma unroll
        for (int d = 1; d < 64; d <<= 1) {
            int u = __shfl_up(val, d, 64);
            if (lane >= d) val += u;
        }
        if (lane == 63) ws2[wv] = val;
    }
    __syncthreads();
    if (t < 256) {
        int woff = 0;
        #pragma unroll
        for (int i = 0; i < 4; ++i) if (i < wv) woff += ws2[i];
        int lexcl = woff + val - v;
        int c = bk * 256 + t;
        if (c < n) {
            row_ptr[c] = s0 + lexcl;
            dis[c] = rsqrtf(2.0f + (float)ews[t] * (1.0f / 16777216.0f));  // deg >= 2
        }
    }
    if (bk == 0 && t == 0) row_ptr[n] = E;
}

// S5: placement: csr[row_ptr[c] + lds_rank] = (r, dis[r]*ew) (one block/bucket, 256 cols)
__global__ __launch_bounds__(512) void k_place(const int2* __restrict__ bxw,
                                               const int* __restrict__ excl,
                                               const int* __restrict__ part, int nparts,
                                               const int* __restrict__ row_ptr,
                                               const float* __restrict__ dis,
                                               int2* __restrict__ csr,
                                               int E, int nblk, int n) {
    __shared__ int cur[256];
    __shared__ int pscan[128], wtot[2];
    int bk = blockIdx.x, t = threadIdx.x;
    if (t < 256) cur[t] = 0;
    scan_parts(part, nparts, pscan, wtot);
    int i0 = bk * nblk;
    int s0 = excl[i0] + pscan[i0 >> 10];
    int s1 = E;
    if (bk + 1 < gridDim.x) {
        int i1 = (bk + 1) * nblk;
        s1 = excl[i1] + pscan[i1 >> 10];
    }
    int cbase = bk * 256;
    for (int p = s0 + t; p < s1; p += 512) {
        int2 u = bxw[p];
        int cl = u.x >> 17, r = u.x & 0x1FFFF;
        int pos = row_ptr[cbase + cl] + atomicAdd(&cur[cl], 1);
        csr[pos] = make_int2(r, __float_as_int(dis[r] * __int_as_float(u.y)));
    }
}

// ---------------- aggregation, paired-gather, unroll 8, 128-thread blocks ----------------
// src/dst bf16 [n][128] = 32 x uint2 per row. One wave per node; half-wave 0 even edges,
// half-wave 1 odd edges; lane covers 4 cols. Combine via __shfl_xor(,32).

template<int OUTMODE>
__global__ __launch_bounds__(128) void k_agg(const uint2* __restrict__ src,
                                             const int* __restrict__ row_ptr,
                                             const int2* __restrict__ csr,
                                             const float* __restrict__ dis,
                                             const float* __restrict__ bias,
                                             uint2* __restrict__ dst, int n) {
    int wid = (blockIdx.x * 128 + threadIdx.x) >> 6;
    int lane = threadIdx.x & 63;
    int hb = lane >> 5, lc = lane & 31;
    if (wid >= n) return;
    int e0 = row_ptr[wid], e1 = row_ptr[wid + 1];

    float p00=0.f,p01=0.f,p02=0.f,p03=0.f;
    float p10=0.f,p11=0.f,p12=0.f,p13=0.f;
    float p20=0.f,p21=0.f,p22=0.f,p23=0.f;
    float p30=0.f,p31=0.f,p32=0.f,p33=0.f;

    int e = e0;
    for (; e + 7 < e1; e += 8) {               // 4 pairs = 8 edges per iter
        int2 c0 = csr[e     + hb];
        int2 c1 = csr[e + 2 + hb];
        int2 c2 = csr[e + 4 + hb];
        int2 c3 = csr[e + 6 + hb];
        uint2 v0 = src[(size_t)c0.x * 32 + lc];
        uint2 v1 = src[(size_t)c1.x * 32 + lc];
        uint2 v2 = src[(size_t)c2.x * 32 + lc];
        uint2 v3 = src[(size_t)c3.x * 32 + lc];
        float w0 = __int_as_float(c0.y), w1 = __int_as_float(c1.y);
        float w2 = __int_as_float(c2.y), w3 = __int_as_float(c3.y);
        p00 += w0 * bfu_lo(v0.x); p01 += w0 * bfu_hi(v0.x);
        p02 += w0 * bfu_lo(v0.y); p03 += w0 * bfu_hi(v0.y);
        p10 += w1 * bfu_lo(v1.x); p11 += w1 * bfu_hi(v1.x);
        p12 += w1 * bfu_lo(v1.y); p13 += w1 * bfu_hi(v1.y);
        p20 += w2 * bfu_lo(v2.x); p21 += w2 * bfu_hi(v2.x);
        p22 += w2 * bfu_lo(v2.y); p23 += w2 * bfu_hi(v2.y);
        p30 += w3 * bfu_lo(v3.x); p31 += w3 * bfu_hi(v3.x);
        p32 += w3 * bfu_lo(v3.y); p33 += w3 * bfu_hi(v3.y);
    }
    for (; e + 1 < e1; e += 2) {               // pair tail
        int2 c = csr[e + hb];
        uint2 v = src[(size_t)c.x * 32 + lc];
        float w = __int_as_float(c.y);
        p00 += w * bfu_lo(v.x); p01 += w * bfu_hi(v.x);
        p02 += w * bfu_lo(v.y); p03 += w * bfu_hi(v.y);
    }
    if (e < e1 && hb == 0) {                   // final odd edge: half A only
        int2 c = csr[e];
        uint2 v = src[(size_t)c.x * 32 + lc];
        float w = __int_as_float(c.y);
        p10 += w * bfu_lo(v.x); p11 += w * bfu_hi(v.x);
        p12 += w * bfu_lo(v.y); p13 += w * bfu_hi(v.y);
    }

    float x0 = (p00 + p10) + (p20 + p30);
    float x1 = (p01 + p11) + (p21 + p31);
    float x2 = (p02 + p12) + (p22 + p32);
    float x3 = (p03 + p13) + (p23 + p33);
    x0 = x0 + __shfl_xor(x0, 32);              // combine halves
    x1 = x1 + __shfl_xor(x1, 32);
    x2 = x2 + __shfl_xor(x2, 32);
    x3 = x3 + __shfl_xor(x3, 32);

    float dc = dis[wid];
    uint2 sv = src[(size_t)wid * 32 + lc];
    float sw = 2.f * dc * dc;
    float o0 = dc * x0 + sw * bfu_lo(sv.x);
    float o1 = dc * x1 + sw * bfu_hi(sv.x);
    float o2 = dc * x2 + sw * bfu_lo(sv.y);
    float o3 = dc * x3 + sw * bfu_hi(sv.y);
    if constexpr (OUTMODE == 0) {
        float4 bv = *(const float4*)(bias + lc * 4);
        o0 += bv.x; o1 += bv.y; o2 += bv.z; o3 += bv.w;
        o0 = fmaxf(o0, 0.f); o1 = fmaxf(o1, 0.f);
        o2 = fmaxf(o2, 0.f); o3 = fmaxf(o3, 0.f);
    }
    if (hb == 0)
        dst[(size_t)wid * 32 + lc] =
            make_uint2((uint)f2bfu(o0) | ((uint)f2bfu(o1) << 16),
                       (uint)f2bfu(o2) | ((uint)f2bfu(o3) << 16));
}

// ---------------- fused mu/var GEMM: [mu|var] = g[n,128](bf16) @ Wcat[128,256] + [bmu|bvar] ----------------

__global__ __launch_bounds__(512) void k_gemm2(const short* __restrict__ A,
                                               const short* __restrict__ Bt,   // [256][128]
                                               const float* __restrict__ bmu,
                                               const float* __restrict__ bvar,
                                               float* __restrict__ out,        // mu at 0, var at n*128
                                               int n) {
    const int K = 128;
    __shared__ short Blds[256 * K];
    int t = threadIdx.x;

    const int CHK = K / 8;   // 16
    for (int c = t; c < 256 * CHK; c += 512) {
        int col = c / CHK;
        int kb  = (c % CHK) * 16;
        int dst = col * (K * 2) + (kb ^ ((col & 7) << 4));
        *(float4*)((char*)Blds + dst) =
            *(const float4*)((const char*)Bt + (size_t)col * (K * 2) + kb);
    }
    __syncthreads();

    int wave = t >> 6, lane = t & 63;
    int lg = lane >> 4, lr = lane & 15;
    int colbase = (wave & 1) * 128;
    long row_base = (long)blockIdx.x * 128 + (wave >> 1) * 32;

    long ra0 = row_base + lr;      if (ra0 > n - 1) ra0 = n - 1;
    long ra1 = row_base + 16 + lr; if (ra1 > n - 1) ra1 = n - 1;

    f32x4 acc[2][8];
    #pragma unroll
    for (int i = 0; i < 2; ++i)
        #pragma unroll
        for (int j = 0; j < 8; ++j) acc[i][j] = (f32x4){0.f, 0.f, 0.f, 0.f};

    const short* pa0 = A + ra0 * K + lg * 8;
    const short* pa1 = A + ra1 * K + lg * 8;

    #pragma unroll
    for (int k0 = 0; k0 < K; k0 += 32) {
        short8 a0 = *(const short8*)(pa0 + k0);
        short8 a1 = *(const short8*)(pa1 + k0);
        int kb = (k0 + lg * 8) * 2;
        #pragma unroll
        for (int cb = 0; cb < 8; ++cb) {
            int col = colbase + cb * 16 + lr;
            short8 b = *(short8*)((char*)Blds + col * (K * 2) + (kb ^ ((col & 7) << 4)));
            acc[0][cb] = __builtin_amdgcn_mfma_f32_16x16x32_bf16(a0, b, acc[0][cb], 0, 0, 0);
            acc[1][cb] = __builtin_amdgcn_mfma_f32_16x16x32_bf16(a1, b, acc[1][cb], 0, 0, 0);
        }
    }

    #pragma unroll
    for (int rf = 0; rf < 2; ++rf) {
        #pragma unroll
        for (int cb = 0; cb < 8; ++cb) {
            int colc = colbase + cb * 16 + lr;
            bool is_var = colc >= 128;
            int col = is_var ? colc - 128 : colc;
            float bv = is_var ? bvar[col] : bmu[col];
            size_t obase = is_var ? (size_t)n * 128 : 0;
            #pragma unroll
            for (int r = 0; r < 4; ++r) {
                long row = row_base + rf * 16 + lg * 4 + r;
                if (row < n)
                    __builtin_nontemporal_store(acc[rf][cb][r] + bv,
                                                &out[obase + (size_t)row * 128 + col]);
            }
        }
    }
}

// ---------------- launch ----------------

extern "C" void kernel_launch(void* const* d_in, const int* in_sizes, int n_in,
                              void* d_out, int out_size, void* d_ws, size_t ws_size,
                              hipStream_t stream) {
    const float* x    = (const float*)d_in[0];
    const int*   ei   = (const int*)d_in[1];   // [2,E]: row then col
    const float* ew   = (const float*)d_in[2];
    const float* W1   = (const float*)d_in[3];
    const float* b1   = (const float*)d_in[4];
    const float* Wmu  = (const float*)d_in[5];
    const float* bmu  = (const float*)d_in[6];
    const float* Wvar = (const float*)d_in[7];
    const float* bvar = (const float*)d_in[8];

    const int E = in_sizes[2];          // 1,600,000
    const int N = in_sizes[0] / 256;    // 100,000
    const int* rowi = ei;
    const int* coli = ei + E;

    char* base = (char*)d_ws;
    size_t off = 0;
    auto alloc = [&](size_t bytes) -> void* {
        void* p = base + off;
        off = (off + bytes + 511) & ~(size_t)511;
        return p;
    };
    const int NBH  = 256;               // histogram AND scatter blocks (must match!)
    const int nbk  = CDIV(N, 256);      // 391 buckets (256 cols each)
    const int nh   = nbk * NBH;         // 100096 histogram entries
    const int nGB  = CDIV(N, 128);      // 782 gemm blocks (128 rows each)
    const int chunkBH = CDIV(E, NBH);   // 6250 edges per hist/scatter block
    const int nparts  = CDIV(nh, 1024); // 98 scanA partials (<=128)

    int*   bhist   = (int*)  alloc((size_t)nh * 4);
    int*   excl    = (int*)  alloc((size_t)nh * 4);
    int*   part    = (int*)  alloc(256 * 4);
    int2*  bxw     = (int2*) alloc((size_t)E * 8);
    int*   row_ptr = (int*)  alloc((size_t)(N + 1) * 4);
    float* dis     = (float*)alloc((size_t)N * 4);
    int2*  csr     = (int2*) alloc((size_t)E * 8);
    uint*  xw      = (uint*) alloc((size_t)N * 64 * 4);  // bf16 [N][128]
    uint*  feat    = (uint*) alloc((size_t)N * 64 * 4);  // bf16 [N][128]
    short* W1t     = (short*)alloc((size_t)256 * 128 * 2);
    short* Wcat    = (short*)alloc((size_t)256 * 128 * 2);
    uint*  g       = xw;   // xw dead after pass-1 aggregation

    // weight prep (W1t needed by fat kernel)
    k_init<<<CDIV(2 * 128 * 256, 512), 512, 0, stream>>>(W1, W1t, Wmu, Wvar, Wcat);

    // GEMM1 || coarse histogram (no global atomics; hist hides under gemm)
    k_fat<<<nGB + NBH, 512, 0, stream>>>(x, W1t, (ushort*)xw, N, nGB,
                                         coli, bhist, E, chunkBH, nbk, NBH);

    // sort: scanA over bhist -> scatter (same NBH/chunkBH) -> fine -> place
    kscanA<<<CDIV(nh, 1024), 256, 0, stream>>>(bhist, excl, part, nh);
    k_bucket<<<NBH, 512, 0, stream>>>(rowi, coli, ew, excl, part, nparts, bxw, E, chunkBH, nbk);
    k_fine2<<<nbk, 512, 0, stream>>>(bxw, excl, part, nparts, row_ptr, dis, E, NBH, N);
    k_place<<<nbk, 512, 0, stream>>>(bxw, excl, part, nparts, row_ptr, dis, csr, E, NBH, N);

    // feat = bf16(relu(A·xw + b1)) ; g = bf16(A·feat) ; [mu|var] = g@[Wmu|Wvar]+[bmu|bvar]
    k_agg<0><<<CDIV(N * 64, 128), 128, 0, stream>>>((const uint2*)xw, row_ptr, csr, dis, b1, (uint2*)feat, N);
    k_agg<1><<<CDIV(N * 64, 128), 128, 0, stream>>>((const uint2*)feat, row_ptr, csr, dis, nullptr, (uint2*)g, N);
    k_gemm2<<<CDIV(N, 128), 512, 0, stream>>>((const short*)g, Wcat, bmu, bvar, (float*)d_out, N);
}

// Round 15
// 254.348 us; speedup vs baseline: 1.0126x; 1.0126x over previous
//
#include <hip/hip_runtime.h>
#include <hip/hip_bf16.h>

#define CDIV(a,b) (((a)+(b)-1)/(b))

typedef __attribute__((ext_vector_type(8))) short short8;   // 8 bf16 (4 VGPRs)
typedef __attribute__((ext_vector_type(4))) float f32x4;    // MFMA C/D frag

static __device__ inline short f2bf(float f) {
    union { __hip_bfloat16 h; short s; } u;
    u.h = __float2bfloat16(f);
    return u.s;
}
static __device__ inline ushort f2bfu(float f) { return (ushort)f2bf(f); }
static __device__ inline float bfu_lo(uint v) { return __uint_as_float(v << 16); }
static __device__ inline float bfu_hi(uint v) { return __uint_as_float(v & 0xffff0000u); }

// ---------------- weight prep ----------------

__global__ __launch_bounds__(512) void k_init(const float* __restrict__ W1,
                                              short* __restrict__ W1t,
                                              const float* __restrict__ Wmu,
                                              const float* __restrict__ Wvar,
                                              short* __restrict__ Wcat) {
    int i = blockIdx.x * 512 + threadIdx.x;
    if (i < 128 * 256) {                       // W1t[col][k] = bf16(W1[k][col]), K=256
        int k = i % 256, col = i / 256;
        W1t[i] = f2bf(W1[(size_t)k * 128 + col]);
    } else if (i < 2 * 128 * 256) {            // Wcat[col][k], K=128: col<128 Wmu, else Wvar
        int j = i - 128 * 256;
        int k = j & 127, col = j >> 7;
        float v = (col < 128) ? Wmu[(size_t)k * 128 + col] : Wvar[(size_t)k * 128 + (col - 128)];
        Wcat[j] = f2bf(v);
    }
}

// ---------------- fat kernel: GEMM1 (blocks < nGB) || coarse histogram (blocks >= nGB) ----------------
// GEMM1: xw[n,128] = bf16( x[n,256] @ W1 ), 8 waves, 256 rows/block, 2 K-phases, 32KB LDS.
// (R14 showed 128-row tiles regress: B-stage bytes per output row double.)
// HIST: bucket = col>>8 (256 cols); per-block LDS histogram -> bhist[bucket*NBH + hb].
// NOTE: scatter (k_bucket) uses the SAME NBH-block / chunkBH decomposition (R11 lesson).

__global__ __launch_bounds__(512) void k_fat(const float* __restrict__ A,
                                             const short* __restrict__ Bt,
                                             ushort* __restrict__ C, int n, int nGB,
                                             const int* __restrict__ coli,
                                             int* __restrict__ bhist,
                                             int E, int chunkBH, int nbk, int NBH) {
    const int K = 256, KH = 128;
    __shared__ short Blds[128 * KH];           // 32 KB (hist path reuses as int*)
    int t = threadIdx.x;

    if (blockIdx.x >= nGB) {                   // ---- histogram path ----
        int* h = (int*)Blds;
        int b = blockIdx.x - nGB;
        for (int i = t; i < nbk; i += 512) h[i] = 0;
        __syncthreads();
        int e0 = b * chunkBH, e1 = min(E, e0 + chunkBH);
        for (int e = e0 + t; e < e1; e += 512)
            atomicAdd(&h[coli[e] >> 8], 1);
        __syncthreads();
        for (int i = t; i < nbk; i += 512)
            bhist[i * NBH + b] = h[i];
        return;
    }

    // ---- GEMM1 path ----
    int wave = t >> 6, lane = t & 63;
    int lg = lane >> 4, lr = lane & 15;
    long row_base = (long)blockIdx.x * 256 + wave * 32;

    long ra0 = row_base + lr;      if (ra0 > n - 1) ra0 = n - 1;   // clamped, stores guarded
    long ra1 = row_base + 16 + lr; if (ra1 > n - 1) ra1 = n - 1;

    f32x4 acc[2][8];
    #pragma unroll
    for (int i = 0; i < 2; ++i)
        #pragma unroll
        for (int j = 0; j < 8; ++j) acc[i][j] = (f32x4){0.f, 0.f, 0.f, 0.f};

    const float* pa0 = A + ra0 * K + lg * 8;
    const float* pa1 = A + ra1 * K + lg * 8;

    #pragma unroll
    for (int p = 0; p < 2; ++p) {
        if (p) __syncthreads();
        const int CHK = KH / 8;
        for (int c = t; c < 128 * CHK; c += 512) {
            int colw = c / CHK;
            int kb  = (c % CHK) * 16;
            int dst = colw * (KH * 2) + (kb ^ ((colw & 7) << 4));
            *(float4*)((char*)Blds + dst) =
                *(const float4*)((const char*)Bt + (size_t)colw * (K * 2) + p * (KH * 2) + kb);
        }
        __syncthreads();

        for (int k0 = 0; k0 < KH; k0 += 32) {
            int kg = p * KH + k0;
            float4 x0 = *(const float4*)(pa0 + kg);
            float4 x1 = *(const float4*)(pa0 + kg + 4);
            float4 y0 = *(const float4*)(pa1 + kg);
            float4 y1 = *(const float4*)(pa1 + kg + 4);
            short8 a0, a1;
            a0[0]=f2bf(x0.x); a0[1]=f2bf(x0.y); a0[2]=f2bf(x0.z); a0[3]=f2bf(x0.w);
            a0[4]=f2bf(x1.x); a0[5]=f2bf(x1.y); a0[6]=f2bf(x1.z); a0[7]=f2bf(x1.w);
            a1[0]=f2bf(y0.x); a1[1]=f2bf(y0.y); a1[2]=f2bf(y0.z); a1[3]=f2bf(y0.w);
            a1[4]=f2bf(y1.x); a1[5]=f2bf(y1.y); a1[6]=f2bf(y1.z); a1[7]=f2bf(y1.w);

            int kb = (k0 + lg * 8) * 2;
            #pragma unroll
            for (int cb = 0; cb < 8; ++cb) {
                int colm = cb * 16 + lr;
                short8 bfr = *(short8*)((char*)Blds + colm * (KH * 2) + (kb ^ ((colm & 7) << 4)));
                acc[0][cb] = __builtin_amdgcn_mfma_f32_16x16x32_bf16(a0, bfr, acc[0][cb], 0, 0, 0);
                acc[1][cb] = __builtin_amdgcn_mfma_f32_16x16x32_bf16(a1, bfr, acc[1][cb], 0, 0, 0);
            }
        }
    }

    #pragma unroll
    for (int rf = 0; rf < 2; ++rf) {
        #pragma unroll
        for (int cb = 0; cb < 8; ++cb) {
            int colm = cb * 16 + lr;
            #pragma unroll
            for (int r = 0; r < 4; ++r) {
                long row = row_base + rf * 16 + lg * 4 + r;
                if (row < n) C[row * 128 + colm] = f2bfu(acc[rf][cb][r]);
            }
        }
    }
}

// ---------------- scan over bhist (A then B; consumers add part[] inline) ----------------

__global__ __launch_bounds__(256) void kscanA(const int* __restrict__ in,
                                              int* __restrict__ out,
                                              int* __restrict__ part, int n) {
    int t = threadIdx.x;
    int base = blockIdx.x * 1024 + t * 4;
    int v0 = (base + 0 < n) ? in[base + 0] : 0;
    int v1 = (base + 1 < n) ? in[base + 1] : 0;
    int v2 = (base + 2 < n) ? in[base + 2] : 0;
    int v3 = (base + 3 < n) ? in[base + 3] : 0;
    int tsum = v0 + v1 + v2 + v3;
    int lane = t & 63, wv = t >> 6;
    int val = tsum;
    #pragma unroll
    for (int d = 1; d < 64; d <<= 1) {
        int u = __shfl_up(val, d, 64);
        if (lane >= d) val += u;
    }
    __shared__ int ws[4];
    if (lane == 63) ws[wv] = val;
    __syncthreads();
    int woff = 0;
    #pragma unroll
    for (int i = 0; i < 4; ++i) if (i < wv) woff += ws[i];
    int excl = woff + val - tsum;
    if (base + 0 < n) out[base + 0] = excl;  excl += v0;
    if (base + 1 < n) out[base + 1] = excl;  excl += v1;
    if (base + 2 < n) out[base + 2] = excl;  excl += v2;
    if (base + 3 < n) out[base + 3] = excl;
    if (t == 255) part[blockIdx.x] = woff + val;
}

__global__ __launch_bounds__(128) void kscanB(int* part, int nb) {
    int t = threadIdx.x;
    int v = (t < nb) ? part[t] : 0;
    int lane = t & 63, wv = t >> 6;
    int val = v;
    #pragma unroll
    for (int d = 1; d < 64; d <<= 1) {
        int u = __shfl_up(val, d, 64);
        if (lane >= d) val += u;
    }
    __shared__ int ws[2];
    if (lane == 63) ws[wv] = val;
    __syncthreads();
    int woff = (wv == 1) ? ws[0] : 0;
    if (t < nb) part[t] = woff + val - v;
}

// S3: scatter edges into bucket-grouped array (LDS cursor per bucket), one 8B store/edge.
// gridDim.x == NBH and chunk == chunkBH (must match histogram decomposition).
__global__ __launch_bounds__(512) void k_bucket(const int* __restrict__ rowi,
                                                const int* __restrict__ coli,
                                                const float* __restrict__ ew,
                                                const int* __restrict__ excl,
                                                const int* __restrict__ part,
                                                int2* __restrict__ bxw,
                                                int E, int chunk, int nbk) {
    __shared__ int cur[512];                   // nbk <= 512
    int b = blockIdx.x, t = threadIdx.x, nblk = gridDim.x;
    for (int i = t; i < nbk; i += 512) cur[i] = 0;
    __syncthreads();
    int e0 = b * chunk, e1 = min(E, e0 + chunk);
    for (int e = e0 + t; e < e1; e += 512) {
        int c = coli[e];
        int bk = c >> 8;
        int idx = bk * nblk + b;
        int pos = excl[idx] + part[idx >> 10] + atomicAdd(&cur[bk], 1);
        bxw[pos] = make_int2(((c & 255) << 17) | rowi[e], __float_as_int(ew[e]));
    }
}

// S4: per-col count + fixed-point ew sum + LOCAL scan -> row_ptr + dis (one block/bucket, 256 cols)
__global__ __launch_bounds__(512) void k_fine2(const int2* __restrict__ bxw,
                                               const int* __restrict__ excl,
                                               const int* __restrict__ part,
                                               int* __restrict__ row_ptr,
                                               float* __restrict__ dis,
                                               int E, int nblk, int n) {
    __shared__ int cnt[256], ews[256];
    __shared__ int ws2[4];
    int bk = blockIdx.x, t = threadIdx.x;
    if (t < 256) { cnt[t] = 0; ews[t] = 0; }
    __syncthreads();
    int i0 = bk * nblk;
    int s0 = excl[i0] + part[i0 >> 10];
    int s1 = E;
    if (bk + 1 < gridDim.x) {
        int i1 = (bk + 1) * nblk;
        s1 = excl[i1] + part[i1 >> 10];
    }
    for (int p = s0 + t; p < s1; p += 512) {
        int2 u = bxw[p];
        int cl = u.x >> 17;
        atomicAdd(&cnt[cl], 1);
        int q = (int)(__int_as_float(u.y) * 16777216.0f + 0.5f);
        atomicAdd(&ews[cl], q);
    }
    __syncthreads();
    // local exclusive scan over cnt[256] (threads 0..255 = waves 0..3)
    int v = 0, val = 0;
    int lane = t & 63, wv = t >> 6;
    if (t < 256) {
        v = cnt[t];
        val = v;
        #pragma unroll
        for (int d = 1; d < 64; d <<= 1) {
            int u = __shfl_up(val, d, 64);
            if (lane >= d) val += u;
        }
        if (lane == 63) ws2[wv] = val;
    }
    __syncthreads();
    if (t < 256) {
        int woff = 0;
        #pragma unroll
        for (int i = 0; i < 4; ++i) if (i < wv) woff += ws2[i];
        int lexcl = woff + val - v;
        int c = bk * 256 + t;
        if (c < n) {
            row_ptr[c] = s0 + lexcl;
            dis[c] = rsqrtf(2.0f + (float)ews[t] * (1.0f / 16777216.0f));  // deg >= 2
        }
    }
    if (bk == 0 && t == 0) row_ptr[n] = E;
}

// S5: placement: csr[row_ptr[c] + lds_rank] = (r, dis[r]*ew) (one block/bucket, 256 cols)
__global__ __launch_bounds__(512) void k_place(const int2* __restrict__ bxw,
                                               const int* __restrict__ excl,
                                               const int* __restrict__ part,
                                               const int* __restrict__ row_ptr,
                                               const float* __restrict__ dis,
                                               int2* __restrict__ csr,
                                               int E, int nblk, int n) {
    __shared__ int cur[256];
    int bk = blockIdx.x, t = threadIdx.x;
    if (t < 256) cur[t] = 0;
    __syncthreads();
    int i0 = bk * nblk;
    int s0 = excl[i0] + part[i0 >> 10];
    int s1 = E;
    if (bk + 1 < gridDim.x) {
        int i1 = (bk + 1) * nblk;
        s1 = excl[i1] + part[i1 >> 10];
    }
    int cbase = bk * 256;
    for (int p = s0 + t; p < s1; p += 512) {
        int2 u = bxw[p];
        int cl = u.x >> 17, r = u.x & 0x1FFFF;
        int pos = row_ptr[cbase + cl] + atomicAdd(&cur[cl], 1);
        csr[pos] = make_int2(r, __float_as_int(dis[r] * __int_as_float(u.y)));
    }
}

// ---------------- aggregation, paired-gather, unroll 8, 128-thread blocks ----------------
// src/dst bf16 [n][128] = 32 x uint2 per row. One wave per node; half-wave 0 even edges,
// half-wave 1 odd edges; lane covers 4 cols. Combine via __shfl_xor(,32).

template<int OUTMODE>
__global__ __launch_bounds__(128) void k_agg(const uint2* __restrict__ src,
                                             const int* __restrict__ row_ptr,
                                             const int2* __restrict__ csr,
                                             const float* __restrict__ dis,
                                             const float* __restrict__ bias,
                                             uint2* __restrict__ dst, int n) {
    int wid = (blockIdx.x * 128 + threadIdx.x) >> 6;
    int lane = threadIdx.x & 63;
    int hb = lane >> 5, lc = lane & 31;
    if (wid >= n) return;
    int e0 = row_ptr[wid], e1 = row_ptr[wid + 1];

    float p00=0.f,p01=0.f,p02=0.f,p03=0.f;
    float p10=0.f,p11=0.f,p12=0.f,p13=0.f;
    float p20=0.f,p21=0.f,p22=0.f,p23=0.f;
    float p30=0.f,p31=0.f,p32=0.f,p33=0.f;

    int e = e0;
    for (; e + 7 < e1; e += 8) {               // 4 pairs = 8 edges per iter
        int2 c0 = csr[e     + hb];
        int2 c1 = csr[e + 2 + hb];
        int2 c2 = csr[e + 4 + hb];
        int2 c3 = csr[e + 6 + hb];
        uint2 v0 = src[(size_t)c0.x * 32 + lc];
        uint2 v1 = src[(size_t)c1.x * 32 + lc];
        uint2 v2 = src[(size_t)c2.x * 32 + lc];
        uint2 v3 = src[(size_t)c3.x * 32 + lc];
        float w0 = __int_as_float(c0.y), w1 = __int_as_float(c1.y);
        float w2 = __int_as_float(c2.y), w3 = __int_as_float(c3.y);
        p00 += w0 * bfu_lo(v0.x); p01 += w0 * bfu_hi(v0.x);
        p02 += w0 * bfu_lo(v0.y); p03 += w0 * bfu_hi(v0.y);
        p10 += w1 * bfu_lo(v1.x); p11 += w1 * bfu_hi(v1.x);
        p12 += w1 * bfu_lo(v1.y); p13 += w1 * bfu_hi(v1.y);
        p20 += w2 * bfu_lo(v2.x); p21 += w2 * bfu_hi(v2.x);
        p22 += w2 * bfu_lo(v2.y); p23 += w2 * bfu_hi(v2.y);
        p30 += w3 * bfu_lo(v3.x); p31 += w3 * bfu_hi(v3.x);
        p32 += w3 * bfu_lo(v3.y); p33 += w3 * bfu_hi(v3.y);
    }
    for (; e + 1 < e1; e += 2) {               // pair tail
        int2 c = csr[e + hb];
        uint2 v = src[(size_t)c.x * 32 + lc];
        float w = __int_as_float(c.y);
        p00 += w * bfu_lo(v.x); p01 += w * bfu_hi(v.x);
        p02 += w * bfu_lo(v.y); p03 += w * bfu_hi(v.y);
    }
    if (e < e1 && hb == 0) {                   // final odd edge: half A only
        int2 c = csr[e];
        uint2 v = src[(size_t)c.x * 32 + lc];
        float w = __int_as_float(c.y);
        p10 += w * bfu_lo(v.x); p11 += w * bfu_hi(v.x);
        p12 += w * bfu_lo(v.y); p13 += w * bfu_hi(v.y);
    }

    float x0 = (p00 + p10) + (p20 + p30);
    float x1 = (p01 + p11) + (p21 + p31);
    float x2 = (p02 + p12) + (p22 + p32);
    float x3 = (p03 + p13) + (p23 + p33);
    x0 = x0 + __shfl_xor(x0, 32);              // combine halves
    x1 = x1 + __shfl_xor(x1, 32);
    x2 = x2 + __shfl_xor(x2, 32);
    x3 = x3 + __shfl_xor(x3, 32);

    float dc = dis[wid];
    uint2 sv = src[(size_t)wid * 32 + lc];
    float sw = 2.f * dc * dc;
    float o0 = dc * x0 + sw * bfu_lo(sv.x);
    float o1 = dc * x1 + sw * bfu_hi(sv.x);
    float o2 = dc * x2 + sw * bfu_lo(sv.y);
    float o3 = dc * x3 + sw * bfu_hi(sv.y);
    if constexpr (OUTMODE == 0) {
        float4 bv = *(const float4*)(bias + lc * 4);
        o0 += bv.x; o1 += bv.y; o2 += bv.z; o3 += bv.w;
        o0 = fmaxf(o0, 0.f); o1 = fmaxf(o1, 0.f);
        o2 = fmaxf(o2, 0.f); o3 = fmaxf(o3, 0.f);
    }
    if (hb == 0)
        dst[(size_t)wid * 32 + lc] =
            make_uint2((uint)f2bfu(o0) | ((uint)f2bfu(o1) << 16),
                       (uint)f2bfu(o2) | ((uint)f2bfu(o3) << 16));
}

// ---------------- fused mu/var GEMM: [mu|var] = g[n,128](bf16) @ Wcat[128,256] + [bmu|bvar] ----------------

__global__ __launch_bounds__(512) void k_gemm2(const short* __restrict__ A,
                                               const short* __restrict__ Bt,   // [256][128]
                                               const float* __restrict__ bmu,
                                               const float* __restrict__ bvar,
                                               float* __restrict__ out,        // mu at 0, var at n*128
                                               int n) {
    const int K = 128;
    __shared__ short Blds[256 * K];
    int t = threadIdx.x;

    const int CHK = K / 8;   // 16
    for (int c = t; c < 256 * CHK; c += 512) {
        int col = c / CHK;
        int kb  = (c % CHK) * 16;
        int dst = col * (K * 2) + (kb ^ ((col & 7) << 4));
        *(float4*)((char*)Blds + dst) =
            *(const float4*)((const char*)Bt + (size_t)col * (K * 2) + kb);
    }
    __syncthreads();

    int wave = t >> 6, lane = t & 63;
    int lg = lane >> 4, lr = lane & 15;
    int colbase = (wave & 1) * 128;
    long row_base = (long)blockIdx.x * 128 + (wave >> 1) * 32;

    long ra0 = row_base + lr;      if (ra0 > n - 1) ra0 = n - 1;
    long ra1 = row_base + 16 + lr; if (ra1 > n - 1) ra1 = n - 1;

    f32x4 acc[2][8];
    #pragma unroll
    for (int i = 0; i < 2; ++i)
        #pragma unroll
        for (int j = 0; j < 8; ++j) acc[i][j] = (f32x4){0.f, 0.f, 0.f, 0.f};

    const short* pa0 = A + ra0 * K + lg * 8;
    const short* pa1 = A + ra1 * K + lg * 8;

    #pragma unroll
    for (int k0 = 0; k0 < K; k0 += 32) {
        short8 a0 = *(const short8*)(pa0 + k0);
        short8 a1 = *(const short8*)(pa1 + k0);
        int kb = (k0 + lg * 8) * 2;
        #pragma unroll
        for (int cb = 0; cb < 8; ++cb) {
            int col = colbase + cb * 16 + lr;
            short8 b = *(short8*)((char*)Blds + col * (K * 2) + (kb ^ ((col & 7) << 4)));
            acc[0][cb] = __builtin_amdgcn_mfma_f32_16x16x32_bf16(a0, b, acc[0][cb], 0, 0, 0);
            acc[1][cb] = __builtin_amdgcn_mfma_f32_16x16x32_bf16(a1, b, acc[1][cb], 0, 0, 0);
        }
    }

    #pragma unroll
    for (int rf = 0; rf < 2; ++rf) {
        #pragma unroll
        for (int cb = 0; cb < 8; ++cb) {
            int colc = colbase + cb * 16 + lr;
            bool is_var = colc >= 128;
            int col = is_var ? colc - 128 : colc;
            float bv = is_var ? bvar[col] : bmu[col];
            size_t obase = is_var ? (size_t)n * 128 : 0;
            #pragma unroll
            for (int r = 0; r < 4; ++r) {
                long row = row_base + rf * 16 + lg * 4 + r;
                if (row < n)
                    __builtin_nontemporal_store(acc[rf][cb][r] + bv,
                                                &out[obase + (size_t)row * 128 + col]);
            }
        }
    }
}

// ---------------- launch ----------------

extern "C" void kernel_launch(void* const* d_in, const int* in_sizes, int n_in,
                              void* d_out, int out_size, void* d_ws, size_t ws_size,
                              hipStream_t stream) {
    const float* x    = (const float*)d_in[0];
    const int*   ei   = (const int*)d_in[1];   // [2,E]: row then col
    const float* ew   = (const float*)d_in[2];
    const float* W1   = (const float*)d_in[3];
    const float* b1   = (const float*)d_in[4];
    const float* Wmu  = (const float*)d_in[5];
    const float* bmu  = (const float*)d_in[6];
    const float* Wvar = (const float*)d_in[7];
    const float* bvar = (const float*)d_in[8];

    const int E = in_sizes[2];          // 1,600,000
    const int N = in_sizes[0] / 256;    // 100,000
    const int* rowi = ei;
    const int* coli = ei + E;

    char* base = (char*)d_ws;
    size_t off = 0;
    auto alloc = [&](size_t bytes) -> void* {
        void* p = base + off;
        off = (off + bytes + 511) & ~(size_t)511;
        return p;
    };
    const int NBH  = 256;               // histogram AND scatter blocks (must match!)
    const int nbk  = CDIV(N, 256);      // 391 buckets (256 cols each)
    const int nh   = nbk * NBH;         // 100096 histogram entries
    const int nGB  = CDIV(N, 256);      // 391 gemm blocks (256 rows each)
    const int chunkBH = CDIV(E, NBH);   // 6250 edges per hist/scatter block

    int*   bhist   = (int*)  alloc((size_t)nh * 4);
    int*   excl    = (int*)  alloc((size_t)nh * 4);
    int*   part    = (int*)  alloc(256 * 4);
    int2*  bxw     = (int2*) alloc((size_t)E * 8);
    int*   row_ptr = (int*)  alloc((size_t)(N + 1) * 4);
    float* dis     = (float*)alloc((size_t)N * 4);
    int2*  csr     = (int2*) alloc((size_t)E * 8);
    uint*  xw      = (uint*) alloc((size_t)N * 64 * 4);  // bf16 [N][128]
    uint*  feat    = (uint*) alloc((size_t)N * 64 * 4);  // bf16 [N][128]
    short* W1t     = (short*)alloc((size_t)256 * 128 * 2);
    short* Wcat    = (short*)alloc((size_t)256 * 128 * 2);
    uint*  g       = xw;   // xw dead after pass-1 aggregation

    // weight prep (W1t needed by fat kernel)
    k_init<<<CDIV(2 * 128 * 256, 512), 512, 0, stream>>>(W1, W1t, Wmu, Wvar, Wcat);

    // GEMM1 || coarse histogram (no global atomics; hist hides under gemm)
    k_fat<<<nGB + NBH, 512, 0, stream>>>(x, W1t, (ushort*)xw, N, nGB,
                                         coli, bhist, E, chunkBH, nbk, NBH);

    // sort: scanA/B over bhist -> scatter (same NBH/chunkBH) -> fine -> place
    kscanA<<<CDIV(nh, 1024), 256, 0, stream>>>(bhist, excl, part, nh);
    kscanB<<<1, 128, 0, stream>>>(part, CDIV(nh, 1024));
    k_bucket<<<NBH, 512, 0, stream>>>(rowi, coli, ew, excl, part, bxw, E, chunkBH, nbk);
    k_fine2<<<nbk, 512, 0, stream>>>(bxw, excl, part, row_ptr, dis, E, NBH, N);
    k_place<<<nbk, 512, 0, stream>>>(bxw, excl, part, row_ptr, dis, csr, E, NBH, N);

    // feat = bf16(relu(A·xw + b1)) ; g = bf16(A·feat) ; [mu|var] = g@[Wmu|Wvar]+[bmu|bvar]
    k_agg<0><<<CDIV(N * 64, 128), 128, 0, stream>>>((const uint2*)xw, row_ptr, csr, dis, b1, (uint2*)feat, N);
    k_agg<1><<<CDIV(N * 64, 128), 128, 0, stream>>>((const uint2*)feat, row_ptr, csr, dis, nullptr, (uint2*)g, N);
    k_gemm2<<<CDIV(N, 128), 512, 0, stream>>>((const short*)g, Wcat, bmu, bvar, (float*)d_out, N);
}